// Round 6
// baseline (167.925 us; speedup 1.0000x reference)
//
#include <hip/hip_runtime.h>

#define NN 16384
#define NE 262144

// ---------------------------------------------------------------------------
// prep: per layer. One wave per node.
//  - G[v][s][o] = sum_i h[v][i] * Ws[i*32+o], s=0..7 from Wk, s=8 from bk
//  - agg[v][o]  = sum_i h[v][i] * root[i*32+o] + b[o]   (edge scatter adds on top)
// ---------------------------------------------------------------------------
__global__ __launch_bounds__(256) void prep_kernel(
    const float* __restrict__ hin, int in_stride, int apply_relu,
    const float* __restrict__ Wk, const float* __restrict__ bk,
    const float* __restrict__ root, const float* __restrict__ bvec,
    float* __restrict__ G, float* __restrict__ agg, int n)
{
    int gtid = blockIdx.x * blockDim.x + threadIdx.x;
    int wid  = gtid >> 6;
    int nw   = (gridDim.x * blockDim.x) >> 6;
    int lane = threadIdx.x & 63;
    int o    = lane & 31;
    int half = lane >> 5;

    float w[5][32];
#pragma unroll
    for (int k = 0; k < 5; ++k) {
        int s = half * 5 + k;
        const float* Ws = (s < 8) ? (Wk + s * 1024) : ((s == 8) ? bk : root);
#pragma unroll
        for (int i = 0; i < 32; ++i) w[k][i] = Ws[i * 32 + o];
    }
    float bo = bvec[o];

    for (int v = wid; v < n; v += nw) {
        float hv = hin[(size_t)v * in_stride + o];
        if (apply_relu) hv = fmaxf(hv, 0.0f);
        float acc0 = 0.f, acc1 = 0.f, acc2 = 0.f, acc3 = 0.f, acc4 = 0.f;
#pragma unroll
        for (int i = 0; i < 32; ++i) {
            float hi = __shfl(hv, i, 64);
            acc0 = fmaf(hi, w[0][i], acc0);
            acc1 = fmaf(hi, w[1][i], acc1);
            acc2 = fmaf(hi, w[2][i], acc2);
            acc3 = fmaf(hi, w[3][i], acc3);
            acc4 = fmaf(hi, w[4][i], acc4);
        }
        float* Gv = G + (size_t)v * 288;
        if (half == 0) {
            Gv[0 * 32 + o] = acc0;
            Gv[1 * 32 + o] = acc1;
            Gv[2 * 32 + o] = acc2;
            Gv[3 * 32 + o] = acc3;
            Gv[4 * 32 + o] = acc4;
        } else {
            Gv[5 * 32 + o] = acc0;
            Gv[6 * 32 + o] = acc1;
            Gv[7 * 32 + o] = acc2;
            Gv[8 * 32 + o] = acc3;               // bias slice
            agg[(size_t)v * 32 + o] = acc4 + bo; // root product + b
        }
    }
}

// ---------------------------------------------------------------------------
// CSR-by-src build (rebuilt every call; deterministic work).
// cnt is used as histogram, then re-zeroed by scan, then reused as cursor.
// ---------------------------------------------------------------------------
__global__ __launch_bounds__(256) void zero_misc(int* __restrict__ cnt,
                                                 float* __restrict__ pooled)
{
    int i = blockIdx.x * blockDim.x + threadIdx.x;
    if (i < NN) cnt[i] = 0;
    if (i < 32) pooled[i] = 0.0f;
}

__global__ __launch_bounds__(256) void hist_kernel(const int* __restrict__ src,
                                                   int* __restrict__ cnt)
{
    int i = blockIdx.x * blockDim.x + threadIdx.x;
    if (i < NE) atomicAdd(&cnt[src[i]], 1);
}

// single-block exclusive scan of cnt[0..NN) -> offs[0..NN]; zeroes cnt.
__global__ __launch_bounds__(1024) void scan_kernel(int* __restrict__ cnt,
                                                    int* __restrict__ offs)
{
    __shared__ int a[1024], b[1024];
    int t = threadIdx.x;
    int base = t * 16;
    int local[16];
    int s = 0;
#pragma unroll
    for (int j = 0; j < 16; ++j) { local[j] = s; s += cnt[base + j]; }
    a[t] = s;
    __syncthreads();
    int* in  = a;
    int* out = b;
    for (int off = 1; off < 1024; off <<= 1) {
        out[t] = in[t] + ((t >= off) ? in[t - off] : 0);
        __syncthreads();
        int* tmp = in; in = out; out = tmp;
    }
    int excl = (t == 0) ? 0 : in[t - 1];
#pragma unroll
    for (int j = 0; j < 16; ++j) { offs[base + j] = excl + local[j]; cnt[base + j] = 0; }
    if (t == 1023) offs[NN] = in[1023];
}

__global__ __launch_bounds__(256) void scatter_kernel(
    const int* __restrict__ src, const int* __restrict__ tgt,
    const float* __restrict__ e, const int* __restrict__ offs,
    int* __restrict__ cnt, int* __restrict__ tgt_s, float* __restrict__ e_s)
{
    int i = blockIdx.x * blockDim.x + threadIdx.x;
    if (i < NE) {
        int sv = src[i];
        int pos = offs[sv] + atomicAdd(&cnt[sv], 1);
        tgt_s[pos] = tgt[i];
        const float4* pe = (const float4*)(e + (size_t)i * 8);
        float4 ea = pe[0];
        float4 eb = pe[1];
        float4* po = (float4*)(e_s + (size_t)pos * 8);
        po[0] = ea;
        po[1] = eb;
    }
}

// ---------------------------------------------------------------------------
// src-major aggregation: half-wave per src node. G row held in registers,
// reused across all out-edges. One line-atomic per edge to agg[tgt].
// ---------------------------------------------------------------------------
__global__ __launch_bounds__(256) void agg_src_kernel(
    const float* __restrict__ e_s, const int* __restrict__ tgt_s,
    const int* __restrict__ offs, const float* __restrict__ G,
    float* __restrict__ agg, int n)
{
    int gtid = blockIdx.x * blockDim.x + threadIdx.x;
    int o    = gtid & 31;
    int hw   = gtid >> 5;
    int nhw  = (gridDim.x * blockDim.x) >> 5;

    for (int v = hw; v < n; v += nhw) {
        const float* g = G + (size_t)v * 288;
        float g0 = g[0 * 32 + o];
        float g1 = g[1 * 32 + o];
        float g2 = g[2 * 32 + o];
        float g3 = g[3 * 32 + o];
        float g4 = g[4 * 32 + o];
        float g5 = g[5 * 32 + o];
        float g6 = g[6 * 32 + o];
        float g7 = g[7 * 32 + o];
        float g8 = g[8 * 32 + o];
        int beg = offs[v];
        int end = offs[v + 1];
        for (int ed = beg; ed < end; ++ed) {
            const float4* pe = (const float4*)(e_s + (size_t)ed * 8);
            float4 ea = pe[0];
            float4 eb = pe[1];
            int t = tgt_s[ed];
            float m = g8;
            m = fmaf(ea.x, g0, m);
            m = fmaf(ea.y, g1, m);
            m = fmaf(ea.z, g2, m);
            m = fmaf(ea.w, g3, m);
            m = fmaf(eb.x, g4, m);
            m = fmaf(eb.y, g5, m);
            m = fmaf(eb.z, g6, m);
            m = fmaf(eb.w, g7, m);
            atomicAdd(agg + (size_t)t * 32 + o, m);
        }
    }
}

// pool: pooled[o] = sum_v relu(agg[v][o])
__global__ __launch_bounds__(256) void pool_kernel(
    const float* __restrict__ agg, float* __restrict__ pooled, int n)
{
    int gtid  = blockIdx.x * blockDim.x + threadIdx.x;
    int o     = gtid & 31;
    int row0  = gtid >> 5;
    int nrows = (gridDim.x * blockDim.x) >> 5;
    float sum = 0.0f;
    for (int v = row0; v < n; v += nrows)
        sum += fmaxf(agg[(size_t)v * 32 + o], 0.0f);
    sum += __shfl_xor(sum, 32, 64);
    if ((threadIdx.x & 63) < 32) atomicAdd(pooled + o, sum);
}

__global__ void final_kernel(const float* __restrict__ pooled,
                             const float* __restrict__ Wd,
                             const float* __restrict__ bd,
                             float* __restrict__ out)
{
    int lane = threadIdx.x;
    float v = (lane < 32) ? pooled[lane] * Wd[lane] : 0.0f;
#pragma unroll
    for (int k = 32; k >= 1; k >>= 1) v += __shfl_xor(v, k, 64);
    if (lane == 0) out[0] = fmaxf(v + bd[0], 0.0f);
}

extern "C" void kernel_launch(void* const* d_in, const int* in_sizes, int n_in,
                              void* d_out, int out_size, void* d_ws, size_t ws_size,
                              hipStream_t stream)
{
    const float* x     = (const float*)d_in[0];
    const int*   src   = (const int*)d_in[1];
    const int*   tgt   = (const int*)d_in[2];
    const float* e     = (const float*)d_in[3];
    const float* Wk1   = (const float*)d_in[4];
    const float* bk1   = (const float*)d_in[5];
    const float* root1 = (const float*)d_in[6];
    const float* b1    = (const float*)d_in[7];
    const float* Wk2   = (const float*)d_in[8];
    const float* bk2   = (const float*)d_in[9];
    const float* root2 = (const float*)d_in[10];
    const float* b2    = (const float*)d_in[11];
    const float* Wd    = (const float*)d_in[12];
    const float* bd    = (const float*)d_in[13];
    float* out = (float*)d_out;

    // workspace layout (all 256B-aligned):
    char* ws = (char*)d_ws;
    size_t off = 0;
    float* agg    = (float*)(ws + off); off += (size_t)NN * 32 * 4;      // 2 MB
    float* pooled = (float*)(ws + off); off += 256;
    float* G      = (float*)(ws + off); off += (size_t)NN * 288 * 4;     // 18.9 MB
    int*   cnt    = (int*)  (ws + off); off += (size_t)NN * 4;           // 64 KB
    int*   offs   = (int*)  (ws + off); off += ((size_t)NN + 64) * 4;    // 64 KB+
    int*   tgt_s  = (int*)  (ws + off); off += (size_t)NE * 4;           // 1 MB
    float* e_s    = (float*)(ws + off); off += (size_t)NE * 8 * 4;       // 8 MB

    // CSR-by-src build (used by both layers)
    zero_misc<<<64, 256, 0, stream>>>(cnt, pooled);
    hist_kernel<<<1024, 256, 0, stream>>>(src, cnt);
    scan_kernel<<<1, 1024, 0, stream>>>(cnt, offs);
    scatter_kernel<<<1024, 256, 0, stream>>>(src, tgt, e, offs, cnt, tgt_s, e_s);

    // layer 1
    prep_kernel<<<512, 256, 0, stream>>>(x, 33, 0, Wk1, bk1, root1, b1, G, agg, NN);
    agg_src_kernel<<<2048, 256, 0, stream>>>(e_s, tgt_s, offs, G, agg, NN);

    // layer 2 (relu on load; in-place agg rewrite is same-wave safe)
    prep_kernel<<<512, 256, 0, stream>>>(agg, 32, 1, Wk2, bk2, root2, b2, G, agg, NN);
    agg_src_kernel<<<2048, 256, 0, stream>>>(e_s, tgt_s, offs, G, agg, NN);

    // pool + final
    pool_kernel<<<64, 256, 0, stream>>>(agg, pooled, NN);
    final_kernel<<<1, 64, 0, stream>>>(pooled, Wd, bd, out);
}